// Round 4
// baseline (222.427 us; speedup 1.0000x reference)
//
#include <hip/hip_runtime.h>
#include <math.h>

// Problem dims (fixed by setup_inputs)
namespace {
constexpr int Bn = 4, Cn = 128, Tn = 32, Hn = 24, Wn = 24, Mn = 3;
constexpr int HWn = Hn * Wn;      // 576
constexpr int TTile = 8;          // time tile per conv block
constexpr int PL = TTile + 2;     // input planes per tile (causal halo 2)
constexpr int RS = 28;            // LDS row stride (1 left pad + 24 data + 3 pad) = 7 float4
constexpr int PSr = 26 * RS;      // plane stride in floats (728)
}

// ---------------- Kernel A: spatial mean pool q -> qg[B*C*T] ----------------
__global__ __launch_bounds__(256) void pool_kernel(const float* __restrict__ q,
                                                   float* __restrict__ qg) {
    int wave = threadIdx.x >> 6;
    int lane = threadIdx.x & 63;
    int plane = blockIdx.x * 4 + wave;
    const float4* p = (const float4*)(q + (size_t)plane * HWn);  // 144 float4
    float4 a = p[lane];
    float4 b = p[lane + 64];
    float s = (a.x + a.y) + (a.z + a.w) + (b.x + b.y) + (b.z + b.w);
    if (lane < 16) {
        float4 c = p[128 + lane];
        s += (c.x + c.y) + (c.z + c.w);
    }
#pragma unroll
    for (int off = 32; off > 0; off >>= 1) s += __shfl_down(s, off);
    if (lane == 0) qg[plane] = s * (1.0f / 576.0f);
}

// ---------------- Kernel B: alpha[B*M*T] from qg ----------------
// thread = (o-pair, t-quad): 2x4 register tile, float4 LDS reads.
__global__ __launch_bounds__(512) void alpha_kernel(const float* __restrict__ qg,
                                                    const float* __restrict__ pre_w,
                                                    const float* __restrict__ pre_b,
                                                    const float* __restrict__ mix_w,
                                                    const float* __restrict__ mix_b,
                                                    float* __restrict__ alpha) {
    __shared__ float qg_s[Cn * Tn];          // [c][t], row = 8 float4
    __shared__ float h_s[Cn * (Tn + 2)];     // [c][t+2], cols 0..1 causal zero pad
    __shared__ float mw_s[Mn * Cn * 3];
    __shared__ float l_s[Mn * Tn];
    int b = blockIdx.x;
    int tid = threadIdx.x;
    for (int i = tid; i < Cn * Tn / 4; i += 512)
        ((float4*)qg_s)[i] = ((const float4*)(qg + b * Cn * Tn))[i];
    for (int i = tid; i < Mn * Cn * 3; i += 512) mw_s[i] = mix_w[i];
    __syncthreads();
    {
        int o0 = (tid >> 3) * 2;             // 2 consecutive o rows
        int t0 = (tid & 7) * 4;              // 4 consecutive t
        float acc0[4] = {0.f, 0.f, 0.f, 0.f};
        float acc1[4] = {0.f, 0.f, 0.f, 0.f};
        const float* w0r = pre_w + (size_t)o0 * Cn;
        const float* w1r = w0r + Cn;
#pragma unroll 4
        for (int cb = 0; cb < Cn; cb += 4) {
            float4 wa = *(const float4*)(w0r + cb);
            float4 wb = *(const float4*)(w1r + cb);
            float w0v[4] = {wa.x, wa.y, wa.z, wa.w};
            float w1v[4] = {wb.x, wb.y, wb.z, wb.w};
            float4 g[4];
#pragma unroll
            for (int j = 0; j < 4; ++j)
                g[j] = *(const float4*)(qg_s + (cb + j) * Tn + t0);
#pragma unroll
            for (int j = 0; j < 4; ++j) {
                acc0[0] += w0v[j] * g[j].x; acc0[1] += w0v[j] * g[j].y;
                acc0[2] += w0v[j] * g[j].z; acc0[3] += w0v[j] * g[j].w;
                acc1[0] += w1v[j] * g[j].x; acc1[1] += w1v[j] * g[j].y;
                acc1[2] += w1v[j] * g[j].z; acc1[3] += w1v[j] * g[j].w;
            }
        }
        float b0 = pre_b[o0], b1 = pre_b[o0 + 1];
        if (t0 == 0) {
            h_s[o0 * (Tn + 2) + 0] = 0.f; h_s[o0 * (Tn + 2) + 1] = 0.f;
            h_s[(o0 + 1) * (Tn + 2) + 0] = 0.f; h_s[(o0 + 1) * (Tn + 2) + 1] = 0.f;
        }
#pragma unroll
        for (int j = 0; j < 4; ++j) {
            float x0 = acc0[j] + b0;
            float x1 = acc1[j] + b1;
            h_s[o0 * (Tn + 2) + 2 + t0 + j] =
                0.5f * x0 * (1.0f + erff(x0 * 0.70710678118654752f));
            h_s[(o0 + 1) * (Tn + 2) + 2 + t0 + j] =
                0.5f * x1 * (1.0f + erff(x1 * 0.70710678118654752f));
        }
    }
    __syncthreads();
    // causal conv1d C->M over time (k=3, left pad 2)
    if (tid < Mn * Tn) {
        int m = tid / Tn, t = tid % Tn;
        float acc = mix_b[m];
#pragma unroll 8
        for (int c = 0; c < Cn; ++c) {
            const float* mw = mw_s + (m * Cn + c) * 3;
            const float* hp = h_s + c * (Tn + 2) + t;  // h[t-2+j] lives at col t+j
            acc += mw[0] * hp[0] + mw[1] * hp[1] + mw[2] * hp[2];
        }
        l_s[m * Tn + t] = acc;
    }
    __syncthreads();
    if (tid < Tn) {
        int t = tid;
        float l0 = l_s[t], l1 = l_s[Tn + t], l2 = l_s[2 * Tn + t];
        float mx = fmaxf(l0, fmaxf(l1, l2));
        float e0 = expf(l0 - mx), e1 = expf(l1 - mx), e2 = expf(l2 - mx);
        float inv = 1.0f / (e0 + e1 + e2);
        alpha[(b * Mn + 0) * Tn + t] = e0 * inv;
        alpha[(b * Mn + 1) * Tn + t] = e1 * inv;
        alpha[(b * Mn + 2) * Tn + t] = e2 * inv;
    }
}

// ---------------- Kernel C: dwconv3d with pre-mixed weights ----------------
// grid: 2*B*C*(T/TTile) blocks of 192; branch (k vs v) in top bid bit.
// thread = (t_local, 2-row pair, 12-col half): 24 outputs, b128 LDS reads.
__global__ __launch_bounds__(192) void conv_kernel(const float* __restrict__ kin,
                                                   const float* __restrict__ vin,
                                                   const float* __restrict__ Wk,
                                                   const float* __restrict__ Wv,
                                                   const float* __restrict__ alpha,
                                                   float* __restrict__ out) {
    __shared__ float s[PL * PSr];         // 10 planes, 26 rows x 28 stride (~28.4 KiB)
    __shared__ float sw[TTile * 27];      // per-t mixed weights

    int bid = blockIdx.x;
    int tt = bid & 3;
    int c  = (bid >> 2) & 127;
    int b  = (bid >> 9) & 3;
    int br = bid >> 11;                   // 0 = k branch, 1 = v branch
    int t0 = tt * TTile;
    int tid = threadIdx.x;
    const size_t plane_base = (size_t)(b * Cn + c) * Tn;
    const float* __restrict__ src = br ? vin : kin;
    const float* __restrict__ Wb  = br ? Wv : Wk;

    // 1) zero-fill LDS (halo + causal pad) + mix weights, then barrier
    float4 z4 = make_float4(0.f, 0.f, 0.f, 0.f);
    for (int i = tid; i < PL * PSr / 4; i += 192) ((float4*)s)[i] = z4;
    for (int i = tid; i < TTile * 27; i += 192) {
        int tl = i / 27;
        int widx = i - tl * 27;
        float a0 = alpha[(b * Mn + 0) * Tn + t0 + tl];
        float a1 = alpha[(b * Mn + 1) * Tn + t0 + tl];
        float a2 = alpha[(b * Mn + 2) * Tn + t0 + tl];
        sw[i] = a0 * Wb[(0 * Cn + c) * 27 + widx]
              + a1 * Wb[(1 * Cn + c) * 27 + widx]
              + a2 * Wb[(2 * Cn + c) * 27 + widx];
    }
    __syncthreads();

    // 2) interior fill: coalesced float4 global loads, plane-level tp check only
    for (int idx = tid; idx < PL * 144; idx += 192) {       // 144 float4 per plane
        int p = idx / 144;
        int cell = idx - p * 144;
        int r = cell / 6;
        int c4 = cell - r * 6;
        int tp = t0 - 2 + p;
        if (tp >= 0) {
            float4 val = *(const float4*)(src + (plane_base + tp) * HWn + r * 24 + c4 * 4);
            float* dst = s + p * PSr + (r + 1) * RS + 1 + c4 * 4;
            dst[0] = val.x; dst[1] = val.y; dst[2] = val.z; dst[3] = val.w;
        }
    }
    __syncthreads();

    // 3) compute: 2 output rows x 12 cols per thread, rows shared across dh
    int tl = tid / 24;
    int rem = tid - tl * 24;
    int h2 = rem >> 1;
    int wseg = rem & 1;
    int h0 = h2 * 2;
    int w0 = wseg * 12;
    const float* wp = sw + tl * 27;
    float acc0[12], acc1[12];
#pragma unroll
    for (int j = 0; j < 12; ++j) { acc0[j] = 0.f; acc1[j] = 0.f; }
#pragma unroll
    for (int dt = 0; dt < 3; ++dt) {
        const float* w9 = wp + dt * 9;
        const float* pb = s + (tl + dt) * PSr + h0 * RS + w0;   // 16B-aligned
#pragma unroll
        for (int j = 0; j < 4; ++j) {                            // padded rows h0..h0+3
            const float4* rp = (const float4*)(pb + j * RS);
            float4 f0 = rp[0], f1 = rp[1], f2 = rp[2], f3 = rp[3];
            float f[16] = {f0.x, f0.y, f0.z, f0.w, f1.x, f1.y, f1.z, f1.w,
                           f2.x, f2.y, f2.z, f2.w, f3.x, f3.y, f3.z, f3.w};
            if (j <= 2) {            // contributes to out row h0 with dh=j
#pragma unroll
                for (int dw = 0; dw < 3; ++dw) {
                    float wc = w9[j * 3 + dw];
#pragma unroll
                    for (int i = 0; i < 12; ++i) acc0[i] += f[i + dw] * wc;
                }
            }
            if (j >= 1) {            // contributes to out row h0+1 with dh=j-1
#pragma unroll
                for (int dw = 0; dw < 3; ++dw) {
                    float wc = w9[(j - 1) * 3 + dw];
#pragma unroll
                    for (int i = 0; i < 12; ++i) acc1[i] += f[i + dw] * wc;
                }
            }
        }
    }
    size_t obase = (plane_base + t0 + tl) * HWn + h0 * Wn + w0;  // float4-aligned
    float* op = out + (br ? (size_t)Bn * Cn * Tn * HWn : 0) + obase;
#pragma unroll
    for (int j = 0; j < 3; ++j) {
        ((float4*)op)[j] = make_float4(acc0[4*j], acc0[4*j+1], acc0[4*j+2], acc0[4*j+3]);
        ((float4*)(op + Wn))[j] = make_float4(acc1[4*j], acc1[4*j+1], acc1[4*j+2], acc1[4*j+3]);
    }
}

extern "C" void kernel_launch(void* const* d_in, const int* in_sizes, int n_in,
                              void* d_out, int out_size, void* d_ws, size_t ws_size,
                              hipStream_t stream) {
    const float* q     = (const float*)d_in[0];
    const float* k     = (const float*)d_in[1];
    const float* v     = (const float*)d_in[2];
    const float* Wk    = (const float*)d_in[3];
    const float* Wv    = (const float*)d_in[4];
    const float* pre_w = (const float*)d_in[5];
    const float* pre_b = (const float*)d_in[6];
    const float* mix_w = (const float*)d_in[7];
    const float* mix_b = (const float*)d_in[8];
    float* out = (float*)d_out;

    float* qg    = (float*)d_ws;            // B*C*T = 16384 floats
    float* alpha = qg + Bn * Cn * Tn;       // B*M*T = 384 floats

    hipLaunchKernelGGL(pool_kernel, dim3(Bn * Cn * Tn / 4), dim3(256), 0, stream, q, qg);
    hipLaunchKernelGGL(alpha_kernel, dim3(Bn), dim3(512), 0, stream,
                       qg, pre_w, pre_b, mix_w, mix_b, alpha);
    hipLaunchKernelGGL(conv_kernel, dim3(2 * Bn * Cn * (Tn / TTile)), dim3(192), 0, stream,
                       k, v, Wk, Wv, alpha, out);
}